// Round 6
// baseline (733.680 us; speedup 1.0000x reference)
//
#include <hip/hip_runtime.h>
#include <hip/hip_bf16.h>
#include <stdint.h>

typedef unsigned short ushort_t;
typedef __bf16 bf16x8 __attribute__((ext_vector_type(8)));
typedef float f32x16 __attribute__((ext_vector_type(16)));

#define BM 128
#define BN 128
#define BK 64   // 16 KB per tile; XOR-swizzled 16B chunks (bank-conflict-free, verified R3)

// ---------- helpers ----------
__device__ inline float b2f(ushort_t u) {
    unsigned int x = ((unsigned int)u) << 16;
    float f; __builtin_memcpy(&f, &x, 4); return f;
}
__device__ inline ushort_t f2b(float f) {
    unsigned int x; __builtin_memcpy(&x, &f, 4);
    unsigned int r = (x + 0x7FFFu + ((x >> 16) & 1u)) >> 16;
    return (ushort_t)r;
}
__device__ inline void stage16(const ushort_t* g, ushort_t* s) {
    __builtin_amdgcn_global_load_lds((const __attribute__((address_space(1))) void*)g,
                                     (__attribute__((address_space(3))) void*)s, 16, 0, 0);
}
// stage one 128x64 bf16 tile; LDS chunk e holds global chunk ((e&7)^(row&7)) of row e>>3
__device__ inline void stage_tile(const ushort_t* G, int ld, int k0, ushort_t* S, int tid) {
#pragma unroll
    for (int t = 0; t < 4; ++t) {
        int e = tid + t * 256;
        int row = e >> 3;
        int sw = ((e & 7) ^ (row & 7)) * 8;
        stage16(G + (long long)row * ld + k0 + sw, &S[e * 8]);
    }
}
__device__ inline bf16x8 ldfrag(const ushort_t* S, int r, int c) {
    return *(const bf16x8*)&S[r * BK + ((c ^ (r & 7)) * 8)];
}
// XCD-aware tile decode (verified R4: FETCH 532->130 MB): XCD = lin%8; XCD k owns a
// fixed set of nx/8 n-tiles (B stays L2-resident), sweeps m, cycling owned n-tiles.
__device__ inline void tile_decode(int& m0, int& n0) {
    const int nx = gridDim.x;
    int lin = blockIdx.y * nx + blockIdx.x;
    if ((nx & 7) == 0) {
        int q = nx >> 3;
        int k = lin & 7, s = lin >> 3;
        n0 = (k * q + s % q) * BN;
        m0 = (s / q) * BM;
    } else {
        m0 = blockIdx.y * BM;
        n0 = blockIdx.x * BN;
    }
}

// 32x32x16 MFMA wave-tile: wave covers 64x64 as 2x2 tiles of 32x32.
// A-frag: lane l holds A[m = l&31][k = ks*16 + (l>>5)*8 + j]  (b128 = chunk ks*2+(l>>5))
// C/D:    col = lane&31, row = (reg&3) + 8*(reg>>2) + 4*(lane>>5)   [guide-verified m74/m101]

// ---------- fused fp32->bf16 convert for x | wgu | proj | wdown (float4-wide) ----------
__global__ void k_cvt4(const float* __restrict__ x, const float* __restrict__ wgu,
                       const float* __restrict__ proj, const float* __restrict__ wdown,
                       ushort_t* __restrict__ xb, ushort_t* __restrict__ gb,
                       ushort_t* __restrict__ pb, ushort_t* __restrict__ wb) {
    int i = blockIdx.x * 256 + threadIdx.x;
    const float* src; ushort_t* dst; int off;
    if (i < 2097152)      { src = x;     dst = xb; off = i; }
    else if (i < 4194304) { src = wgu;   dst = gb; off = i - 2097152; }
    else if (i < 4456448) { src = proj;  dst = pb; off = i - 4194304; }
    else                  { src = wdown; dst = wb; off = i - 4456448; }
    float4 v = ((const float4*)src)[off];
    ushort4 o; o.x = f2b(v.x); o.y = f2b(v.y); o.z = f2b(v.z); o.w = f2b(v.w);
    ((ushort4*)dst)[off] = o;
}

// ---------- causal depthwise conv (K=5), fp32 in, bf16 out ----------
__global__ void k_conv(const float* __restrict__ x, const float* __restrict__ w,
                       const float* __restrict__ bias, ushort_t* __restrict__ out,
                       int T, int D, int n) {
    int idx = blockIdx.x * blockDim.x + threadIdx.x;
    if (idx >= n) return;
    int d = idx % D;
    int t = (idx / D) % T;
    int b = idx / (D * T);
    float acc = bias[d];
#pragma unroll
    for (int k = 0; k < 5; ++k) {
        int ts = t - 4 + k;
        if (ts >= 0) acc += x[(long long)b * T * D + (long long)ts * D + d] * w[d * 5 + k];
    }
    out[idx] = f2b(acc);
}

// ---------- batched bf16 NT GEMM (bf16 out): C[m,n] = scale * sum_k A[m,k]*B[n,k] ----------
__global__ __launch_bounds__(256, 4)
void k_gemm_nt(const ushort_t* __restrict__ A, const ushort_t* __restrict__ B,
               ushort_t* __restrict__ C, int K, int lda, int ldb, int ldc,
               long long sAb, long long sBb, long long sCb, float scale) {
    __shared__ __attribute__((aligned(16))) ushort_t sA[BM * BK];
    __shared__ __attribute__((aligned(16))) ushort_t sB[BN * BK];

    int m0, n0;
    tile_decode(m0, n0);
    const int bb = blockIdx.z;
    const ushort_t* Ab = A + bb * sAb + (long long)m0 * lda;
    const ushort_t* Bb = B + bb * sBb + (long long)n0 * ldb;

    const int tid = threadIdx.x;
    const int lane = tid & 63, l32 = lane & 31, half = lane >> 5;
    const int wave = tid >> 6;
    const int wm = (wave >> 1) * 64, wn = (wave & 1) * 64;

    f32x16 acc[2][2];
#pragma unroll
    for (int i = 0; i < 2; ++i)
#pragma unroll
        for (int j = 0; j < 2; ++j) acc[i][j] = (f32x16)(0.f);

    for (int k0 = 0; k0 < K; k0 += BK) {
        __syncthreads();
        stage_tile(Ab, lda, k0, sA, tid);
        stage_tile(Bb, ldb, k0, sB, tid);
        __syncthreads();
#pragma unroll
        for (int ks = 0; ks < 4; ++ks) {
            bf16x8 af[2], bfr[2];
#pragma unroll
            for (int mi = 0; mi < 2; ++mi)
                af[mi] = ldfrag(sA, wm + mi * 32 + l32, ks * 2 + half);
#pragma unroll
            for (int nj = 0; nj < 2; ++nj)
                bfr[nj] = ldfrag(sB, wn + nj * 32 + l32, ks * 2 + half);
#pragma unroll
            for (int mi = 0; mi < 2; ++mi)
#pragma unroll
                for (int nj = 0; nj < 2; ++nj)
                    acc[mi][nj] = __builtin_amdgcn_mfma_f32_32x32x16_bf16(af[mi], bfr[nj], acc[mi][nj], 0, 0, 0);
        }
    }

    ushort_t* Cp = C + bb * sCb;
#pragma unroll
    for (int mi = 0; mi < 2; ++mi)
#pragma unroll
        for (int nj = 0; nj < 2; ++nj) {
            int col = n0 + wn + nj * 32 + l32;
#pragma unroll
            for (int reg = 0; reg < 16; ++reg) {
                int row = m0 + wm + mi * 32 + (reg & 3) + 8 * (reg >> 2) + 4 * half;
                Cp[(long long)row * ldc + col] = f2b(acc[mi][nj][reg] * scale);
            }
        }
}

// ---------- fused gate_up GEMM + SiLU: h = silu(x@Wg^T) * (x@Wu^T) ----------
__global__ __launch_bounds__(256)
void k_gemm_silu(const ushort_t* __restrict__ A, const ushort_t* __restrict__ Bg,
                 const ushort_t* __restrict__ Bu, ushort_t* __restrict__ H,
                 int K, int lda, int ldb, int ldh) {
    __shared__ __attribute__((aligned(16))) ushort_t sA[BM * BK];
    __shared__ __attribute__((aligned(16))) ushort_t sBg[BN * BK];
    __shared__ __attribute__((aligned(16))) ushort_t sBu[BN * BK];

    int m0, n0;
    tile_decode(m0, n0);
    const ushort_t* Ab = A + (long long)m0 * lda;
    const ushort_t* Bgb = Bg + (long long)n0 * ldb;
    const ushort_t* Bub = Bu + (long long)n0 * ldb;

    const int tid = threadIdx.x;
    const int lane = tid & 63, l32 = lane & 31, half = lane >> 5;
    const int wave = tid >> 6;
    const int wm = (wave >> 1) * 64, wn = (wave & 1) * 64;

    f32x16 ag[2][2], au[2][2];
#pragma unroll
    for (int i = 0; i < 2; ++i)
#pragma unroll
        for (int j = 0; j < 2; ++j) { ag[i][j] = (f32x16)(0.f); au[i][j] = (f32x16)(0.f); }

    for (int k0 = 0; k0 < K; k0 += BK) {
        __syncthreads();
        stage_tile(Ab, lda, k0, sA, tid);
        stage_tile(Bgb, ldb, k0, sBg, tid);
        stage_tile(Bub, ldb, k0, sBu, tid);
        __syncthreads();
#pragma unroll
        for (int ks = 0; ks < 4; ++ks) {
            bf16x8 af[2], bg[2], bu[2];
#pragma unroll
            for (int mi = 0; mi < 2; ++mi)
                af[mi] = ldfrag(sA, wm + mi * 32 + l32, ks * 2 + half);
#pragma unroll
            for (int nj = 0; nj < 2; ++nj) {
                bg[nj] = ldfrag(sBg, wn + nj * 32 + l32, ks * 2 + half);
                bu[nj] = ldfrag(sBu, wn + nj * 32 + l32, ks * 2 + half);
            }
#pragma unroll
            for (int mi = 0; mi < 2; ++mi)
#pragma unroll
                for (int nj = 0; nj < 2; ++nj) {
                    ag[mi][nj] = __builtin_amdgcn_mfma_f32_32x32x16_bf16(af[mi], bg[nj], ag[mi][nj], 0, 0, 0);
                    au[mi][nj] = __builtin_amdgcn_mfma_f32_32x32x16_bf16(af[mi], bu[nj], au[mi][nj], 0, 0, 0);
                }
        }
    }

#pragma unroll
    for (int mi = 0; mi < 2; ++mi)
#pragma unroll
        for (int nj = 0; nj < 2; ++nj) {
            int col = n0 + wn + nj * 32 + l32;
#pragma unroll
            for (int reg = 0; reg < 16; ++reg) {
                int row = m0 + wm + mi * 32 + (reg & 3) + 8 * (reg >> 2) + 4 * half;
                float g = ag[mi][nj][reg], u = au[mi][nj][reg];
                float s = g / (1.f + __expf(-g));
                H[(long long)row * ldh + col] = f2b(s * u);
            }
        }
}

// ---------- triangular P GEMM: P[b, i*256+m, j*256+n] = sum_f h_i[m,f] h_j[n,f], j<i ----------
// 1D grid of 960; decode keeps the 4 tiles of one pair on ONE XCD (lin%8 == pair%8)
// and consecutive same-i pairs on the same XCD (h_i stays L2-hot).
__global__ __launch_bounds__(256, 4)
void k_gemm_tri(const ushort_t* __restrict__ H, ushort_t* __restrict__ P,
                int K, int ldh, int ldp, long long sHb, long long sPb) {
    __shared__ __attribute__((aligned(16))) ushort_t sA[BM * BK];
    __shared__ __attribute__((aligned(16))) ushort_t sB[BN * BK];

    const int lin = blockIdx.x;
    const int g = lin >> 5, w = lin & 31;
    const int xk = w & 7, t = w >> 3;
    int pairIdx = g * 8 + xk;            // 0..239
    const int bb = pairIdx / 120;
    int p = pairIdx % 120;
    int i = 1, rem = p;
    while (rem >= i) { rem -= i; ++i; }
    const int j = rem;
    const int m0 = (t >> 1) * BM, n0 = (t & 1) * BN;

    const ushort_t* Ab = H + bb * sHb + (long long)(i * 256 + m0) * ldh;
    const ushort_t* Bb = H + bb * sHb + (long long)(j * 256 + n0) * ldh;

    const int tid = threadIdx.x;
    const int lane = tid & 63, l32 = lane & 31, half = lane >> 5;
    const int wave = tid >> 6;
    const int wm = (wave >> 1) * 64, wn = (wave & 1) * 64;

    f32x16 acc[2][2];
#pragma unroll
    for (int a = 0; a < 2; ++a)
#pragma unroll
        for (int c = 0; c < 2; ++c) acc[a][c] = (f32x16)(0.f);

    for (int k0 = 0; k0 < K; k0 += BK) {
        __syncthreads();
        stage_tile(Ab, ldh, k0, sA, tid);
        stage_tile(Bb, ldh, k0, sB, tid);
        __syncthreads();
#pragma unroll
        for (int ks = 0; ks < 4; ++ks) {
            bf16x8 af[2], bfr[2];
#pragma unroll
            for (int mi = 0; mi < 2; ++mi)
                af[mi] = ldfrag(sA, wm + mi * 32 + l32, ks * 2 + half);
#pragma unroll
            for (int nj = 0; nj < 2; ++nj)
                bfr[nj] = ldfrag(sB, wn + nj * 32 + l32, ks * 2 + half);
#pragma unroll
            for (int mi = 0; mi < 2; ++mi)
#pragma unroll
                for (int nj = 0; nj < 2; ++nj)
                    acc[mi][nj] = __builtin_amdgcn_mfma_f32_32x32x16_bf16(af[mi], bfr[nj], acc[mi][nj], 0, 0, 0);
        }
    }

    ushort_t* Pp = P + bb * sPb;
#pragma unroll
    for (int mi = 0; mi < 2; ++mi)
#pragma unroll
        for (int nj = 0; nj < 2; ++nj) {
            int col = j * 256 + n0 + wn + nj * 32 + l32;
#pragma unroll
            for (int reg = 0; reg < 16; ++reg) {
                int row = i * 256 + m0 + wm + mi * 32 + (reg & 3) + 8 * (reg >> 2) + 4 * half;
                Pp[(long long)row * ldp + col] = f2b(acc[mi][nj][reg]);
            }
        }
}

// ---------- fused output GEMM: out[b,i] = [h_i | P_i,0:i*C] @ [wdown | tpT]^T ----------
// K = 4096 + i*256; all operand lds are 4096. LR pre-folded into tpT. fp32 store.
__global__ __launch_bounds__(256, 4)
void k_gemm_out(const ushort_t* __restrict__ h, const ushort_t* __restrict__ wdown,
                const ushort_t* __restrict__ P, const ushort_t* __restrict__ tpT,
                float* __restrict__ out) {
    constexpr int T = 4096, D = 1024, F = 4096, C = 256, K1 = 4096;
    __shared__ __attribute__((aligned(16))) ushort_t sA[BM * BK];
    __shared__ __attribute__((aligned(16))) ushort_t sB[BN * BK];

    const int z = blockIdx.z, bb = z >> 4, ii = z & 15;
    const int K2 = ii * C;
    int m0, n0;
    tile_decode(m0, n0);

    const ushort_t* A1 = h + (long long)bb * T * F + (long long)(ii * C + m0) * F;
    const ushort_t* B1 = wdown + (long long)n0 * F;
    const ushort_t* A2 = P + (long long)bb * T * T + (long long)(ii * C + m0) * T;
    const ushort_t* B2 = tpT + (long long)bb * D * T + (long long)n0 * T;

    const int tid = threadIdx.x;
    const int lane = tid & 63, l32 = lane & 31, half = lane >> 5;
    const int wave = tid >> 6;
    const int wm = (wave >> 1) * 64, wn = (wave & 1) * 64;

    f32x16 acc[2][2];
#pragma unroll
    for (int i = 0; i < 2; ++i)
#pragma unroll
        for (int j = 0; j < 2; ++j) acc[i][j] = (f32x16)(0.f);

    const int K = K1 + K2;
    for (int k0 = 0; k0 < K; k0 += BK) {
        const ushort_t* As = (k0 < K1) ? A1 + k0 : A2 + (k0 - K1);
        const ushort_t* Bs = (k0 < K1) ? B1 + k0 : B2 + (k0 - K1);
        __syncthreads();
        stage_tile(As, 4096, 0, sA, tid);
        stage_tile(Bs, 4096, 0, sB, tid);
        __syncthreads();
#pragma unroll
        for (int ks = 0; ks < 4; ++ks) {
            bf16x8 af[2], bfr[2];
#pragma unroll
            for (int mi = 0; mi < 2; ++mi)
                af[mi] = ldfrag(sA, wm + mi * 32 + l32, ks * 2 + half);
#pragma unroll
            for (int nj = 0; nj < 2; ++nj)
                bfr[nj] = ldfrag(sB, wn + nj * 32 + l32, ks * 2 + half);
#pragma unroll
            for (int mi = 0; mi < 2; ++mi)
#pragma unroll
                for (int nj = 0; nj < 2; ++nj)
                    acc[mi][nj] = __builtin_amdgcn_mfma_f32_32x32x16_bf16(af[mi], bfr[nj], acc[mi][nj], 0, 0, 0);
        }
    }

    float* Op = out + (long long)bb * T * D + (long long)ii * C * D;
#pragma unroll
    for (int mi = 0; mi < 2; ++mi)
#pragma unroll
        for (int nj = 0; nj < 2; ++nj) {
            int col = n0 + wn + nj * 32 + l32;
#pragma unroll
            for (int reg = 0; reg < 16; ++reg) {
                int row = m0 + wm + mi * 32 + (reg & 3) + 8 * (reg >> 2) + 4 * half;
                Op[(long long)row * D + col] = acc[mi][nj][reg];
            }
        }
}

// ---------- launch ----------
extern "C" void kernel_launch(void* const* d_in, const int* in_sizes, int n_in,
                              void* d_out, int out_size, void* d_ws, size_t ws_size,
                              hipStream_t stream) {
    const float* x         = (const float*)d_in[0];
    const float* ttt_tgt   = (const float*)d_in[1];
    const float* w_gate_up = (const float*)d_in[2];
    const float* w_down    = (const float*)d_in[3];
    const float* ttt_proj  = (const float*)d_in[4];
    const float* conv_w    = (const float*)d_in[5];
    const float* conv_b    = (const float*)d_in[6];
    float* out = (float*)d_out;
    (void)in_sizes; (void)n_in; (void)out_size; (void)ws_size;

    constexpr int Bb = 2, T = 4096, D = 1024, F = 4096, C = 256;
    constexpr float LR = 0.01f;

    // workspace (154 MB):
    //   [0,64M): x_bf(16M) | wgu_bf(16M) | t_bf(16M) | scratch  -> later aliased by P (B,T,T) bf16
    //   [64M..): proj_bf 2M | wdown_bf 8M | tpT 16M | h 64M
    char* ws = (char*)d_ws;
    ushort_t* x_bf     = (ushort_t*)(ws);
    ushort_t* wgu_bf   = (ushort_t*)(ws + 16777216LL);
    ushort_t* t_bf     = (ushort_t*)(ws + 2 * 16777216LL);
    ushort_t* P        = (ushort_t*)(ws);
    ushort_t* proj_bf  = (ushort_t*)(ws + 67108864LL);
    ushort_t* wdown_bf = (ushort_t*)(ws + 67108864LL + 2097152LL);
    ushort_t* tpT      = (ushort_t*)(ws + 67108864LL + 2097152LL + 8388608LL);
    ushort_t* h        = (ushort_t*)(ws + 67108864LL + 2097152LL + 8388608LL + 16777216LL);

    // 1) fused converts (x | wgu | proj | wdown), float4-wide
    k_cvt4<<<21504, 256, 0, stream>>>(x, w_gate_up, ttt_proj, w_down,
                                      x_bf, wgu_bf, proj_bf, wdown_bf);

    // 2) causal depthwise conv -> t_bf (B,T,D) bf16
    k_conv<<<(Bb * T * D) / 256, 256, 0, stream>>>(ttt_tgt, conv_w, conv_b, t_bf, T, D, Bb * T * D);

    // 3) tpT[b] = LR * (proj @ t[b]^T) : M=D, N=T, K=D -> bf16 (B,D,T)
    k_gemm_nt<<<dim3(T / BN, D / BM, Bb), 256, 0, stream>>>(
        proj_bf, t_bf, tpT, D, D, D, T,
        0, (long long)T * D, (long long)D * T, LR);

    // 4) h = silu(x@Wg^T)*(x@Wu^T) : M=B*T, N=F, K=D
    k_gemm_silu<<<dim3(F / BN, (Bb * T) / BM, 1), 256, 0, stream>>>(
        x_bf, wgu_bf, wgu_bf + (long long)F * D, h, D, D, D, F);

    // 5) P lower chunk-blocks: P[b, i*C.., j*C..] = h_i h_j^T, j<i  (XCD-coherent 1D grid)
    k_gemm_tri<<<dim3(960, 1, 1), 256, 0, stream>>>(
        h, P, F, F, T, (long long)T * F, (long long)T * T);

    // 6) out[b,i] = [h_i | P] @ [wdown | LR*tpT]^T  (variable K = 4096 + i*256)
    k_gemm_out<<<dim3(D / BN, C / BM, Bb * 16), 256, 0, stream>>>(
        h, wdown_bf, P, tpT, out);
}

// Round 7
// 691.196 us; speedup vs baseline: 1.0615x; 1.0615x over previous
//
#include <hip/hip_runtime.h>
#include <hip/hip_bf16.h>
#include <stdint.h>

typedef unsigned short ushort_t;
typedef __bf16 bf16x8 __attribute__((ext_vector_type(8)));
typedef float f32x16 __attribute__((ext_vector_type(16)));

#define BM 128
#define BN 128
#define BK 64   // 16 KB per tile; XOR-swizzled 16B chunks

// ---------- helpers ----------
__device__ inline float b2f(ushort_t u) {
    unsigned int x = ((unsigned int)u) << 16;
    float f; __builtin_memcpy(&f, &x, 4); return f;
}
__device__ inline ushort_t f2b(float f) {
    unsigned int x; __builtin_memcpy(&x, &f, 4);
    unsigned int r = (x + 0x7FFFu + ((x >> 16) & 1u)) >> 16;
    return (ushort_t)r;
}
__device__ inline void stage16(const ushort_t* g, ushort_t* s) {
    __builtin_amdgcn_global_load_lds((const __attribute__((address_space(1))) void*)g,
                                     (__attribute__((address_space(3))) void*)s, 16, 0, 0);
}
// swizzle position function: folds row bits 3-4 so stride-8 lane groups (HW b128
// conflict granularity; inferred R5/R6 counter A/B) never exceed 2-way.
__device__ inline int swz(int r) { return (r & 7) ^ ((r >> 3) & 3); }
// stage one 128x64 bf16 tile; LDS slot e (row e>>3, pos e&7) holds global chunk (e&7)^swz(row)
__device__ inline void stage_tile(const ushort_t* G, int ld, int k0, ushort_t* S, int tid) {
#pragma unroll
    for (int t = 0; t < 4; ++t) {
        int e = tid + t * 256;
        int row = e >> 3;
        int sw = ((e & 7) ^ swz(row)) * 8;
        stage16(G + (long long)row * ld + k0 + sw, &S[e * 8]);
    }
}
__device__ inline bf16x8 ldfrag(const ushort_t* S, int r, int c) {
    return *(const bf16x8*)&S[r * BK + ((c ^ swz(r)) * 8)];
}
// XCD-aware tile decode (verified R4: FETCH 532->130 MB): XCD = lin%8; XCD k owns a
// fixed set of nx/8 n-tiles (B stays L2-resident), sweeps m, cycling owned n-tiles.
__device__ inline void tile_decode(int& m0, int& n0) {
    const int nx = gridDim.x;
    int lin = blockIdx.y * nx + blockIdx.x;
    if ((nx & 7) == 0) {
        int q = nx >> 3;
        int k = lin & 7, s = lin >> 3;
        n0 = (k * q + s % q) * BN;
        m0 = (s / q) * BM;
    } else {
        m0 = blockIdx.y * BM;
        n0 = blockIdx.x * BN;
    }
}

// 32x32x16 MFMA wave-tile: wave covers 64x64 as 2x2 tiles of 32x32.
// A-frag: lane l holds A[m = l&31][k = ks*16 + (l>>5)*8 + j]
// C/D:    col = lane&31, row = (reg&3) + 8*(reg>>2) + 4*(lane>>5)   [guide-verified m74/m101]

// ---------- fused prep: fp32->bf16 converts (x|wgu|proj|wdown) + causal conv ----------
__global__ void k_prep(const float* __restrict__ x, const float* __restrict__ wgu,
                       const float* __restrict__ proj, const float* __restrict__ wdown,
                       const float* __restrict__ tt, const float* __restrict__ cw,
                       const float* __restrict__ cb,
                       ushort_t* __restrict__ xb, ushort_t* __restrict__ gb,
                       ushort_t* __restrict__ pb, ushort_t* __restrict__ wb,
                       ushort_t* __restrict__ tb) {
    constexpr int T = 4096, D = 1024;
    int blk = blockIdx.x;
    if (blk < 21504) {
        // converts, float4-wide: x 2097152 | wgu 2097152 | proj 262144 | wdown 1048576 units
        int i = blk * 256 + threadIdx.x;
        const float* src; ushort_t* dst; int off;
        if (i < 2097152)      { src = x;     dst = xb; off = i; }
        else if (i < 4194304) { src = wgu;   dst = gb; off = i - 2097152; }
        else if (i < 4456448) { src = proj;  dst = pb; off = i - 4194304; }
        else                  { src = wdown; dst = wb; off = i - 4456448; }
        float4 v = ((const float4*)src)[off];
        ushort4 o; o.x = f2b(v.x); o.y = f2b(v.y); o.z = f2b(v.z); o.w = f2b(v.w);
        ((ushort4*)dst)[off] = o;
    } else {
        // causal depthwise conv (K=5)
        int idx = (blk - 21504) * 256 + threadIdx.x;
        int d = idx % D;
        int t = (idx / D) % T;
        int b = idx / (D * T);
        float acc = cb[d];
#pragma unroll
        for (int k = 0; k < 5; ++k) {
            int ts = t - 4 + k;
            if (ts >= 0) acc += tt[(long long)b * T * D + (long long)ts * D + d] * cw[d * 5 + k];
        }
        tb[idx] = f2b(acc);
    }
}

// ---------- batched bf16 NT GEMM (bf16 out): C[m,n] = scale * sum_k A[m,k]*B[n,k] ----------
__global__ __launch_bounds__(256, 4)
void k_gemm_nt(const ushort_t* __restrict__ A, const ushort_t* __restrict__ B,
               ushort_t* __restrict__ C, int K, int lda, int ldb, int ldc,
               long long sAb, long long sBb, long long sCb, float scale) {
    __shared__ __attribute__((aligned(16))) ushort_t sA[BM * BK];
    __shared__ __attribute__((aligned(16))) ushort_t sB[BN * BK];

    int m0, n0;
    tile_decode(m0, n0);
    const int bb = blockIdx.z;
    const ushort_t* Ab = A + bb * sAb + (long long)m0 * lda;
    const ushort_t* Bb = B + bb * sBb + (long long)n0 * ldb;

    const int tid = threadIdx.x;
    const int lane = tid & 63, l32 = lane & 31, half = lane >> 5;
    const int wave = tid >> 6;
    const int wm = (wave >> 1) * 64, wn = (wave & 1) * 64;

    f32x16 acc[2][2];
#pragma unroll
    for (int i = 0; i < 2; ++i)
#pragma unroll
        for (int j = 0; j < 2; ++j) acc[i][j] = (f32x16)(0.f);

    for (int k0 = 0; k0 < K; k0 += BK) {
        __syncthreads();
        stage_tile(Ab, lda, k0, sA, tid);
        stage_tile(Bb, ldb, k0, sB, tid);
        __syncthreads();
#pragma unroll
        for (int ks = 0; ks < 4; ++ks) {
            bf16x8 af[2], bfr[2];
#pragma unroll
            for (int mi = 0; mi < 2; ++mi)
                af[mi] = ldfrag(sA, wm + mi * 32 + l32, ks * 2 + half);
#pragma unroll
            for (int nj = 0; nj < 2; ++nj)
                bfr[nj] = ldfrag(sB, wn + nj * 32 + l32, ks * 2 + half);
#pragma unroll
            for (int mi = 0; mi < 2; ++mi)
#pragma unroll
                for (int nj = 0; nj < 2; ++nj)
                    acc[mi][nj] = __builtin_amdgcn_mfma_f32_32x32x16_bf16(af[mi], bfr[nj], acc[mi][nj], 0, 0, 0);
        }
    }

    ushort_t* Cp = C + bb * sCb;
#pragma unroll
    for (int mi = 0; mi < 2; ++mi)
#pragma unroll
        for (int nj = 0; nj < 2; ++nj) {
            int col = n0 + wn + nj * 32 + l32;
#pragma unroll
            for (int reg = 0; reg < 16; ++reg) {
                int row = m0 + wm + mi * 32 + (reg & 3) + 8 * (reg >> 2) + 4 * half;
                Cp[(long long)row * ldc + col] = f2b(acc[mi][nj][reg] * scale);
            }
        }
}

// ---------- fused gate_up GEMM + SiLU: h = silu(x@Wg^T) * (x@Wu^T) ----------
__global__ __launch_bounds__(256)
void k_gemm_silu(const ushort_t* __restrict__ A, const ushort_t* __restrict__ Bg,
                 const ushort_t* __restrict__ Bu, ushort_t* __restrict__ H,
                 int K, int lda, int ldb, int ldh) {
    __shared__ __attribute__((aligned(16))) ushort_t sA[BM * BK];
    __shared__ __attribute__((aligned(16))) ushort_t sBg[BN * BK];
    __shared__ __attribute__((aligned(16))) ushort_t sBu[BN * BK];

    int m0, n0;
    tile_decode(m0, n0);
    const ushort_t* Ab = A + (long long)m0 * lda;
    const ushort_t* Bgb = Bg + (long long)n0 * ldb;
    const ushort_t* Bub = Bu + (long long)n0 * ldb;

    const int tid = threadIdx.x;
    const int lane = tid & 63, l32 = lane & 31, half = lane >> 5;
    const int wave = tid >> 6;
    const int wm = (wave >> 1) * 64, wn = (wave & 1) * 64;

    f32x16 ag[2][2], au[2][2];
#pragma unroll
    for (int i = 0; i < 2; ++i)
#pragma unroll
        for (int j = 0; j < 2; ++j) { ag[i][j] = (f32x16)(0.f); au[i][j] = (f32x16)(0.f); }

    for (int k0 = 0; k0 < K; k0 += BK) {
        __syncthreads();
        stage_tile(Ab, lda, k0, sA, tid);
        stage_tile(Bgb, ldb, k0, sBg, tid);
        stage_tile(Bub, ldb, k0, sBu, tid);
        __syncthreads();
#pragma unroll
        for (int ks = 0; ks < 4; ++ks) {
            bf16x8 af[2], bg[2], bu[2];
#pragma unroll
            for (int mi = 0; mi < 2; ++mi)
                af[mi] = ldfrag(sA, wm + mi * 32 + l32, ks * 2 + half);
#pragma unroll
            for (int nj = 0; nj < 2; ++nj) {
                bg[nj] = ldfrag(sBg, wn + nj * 32 + l32, ks * 2 + half);
                bu[nj] = ldfrag(sBu, wn + nj * 32 + l32, ks * 2 + half);
            }
#pragma unroll
            for (int mi = 0; mi < 2; ++mi)
#pragma unroll
                for (int nj = 0; nj < 2; ++nj) {
                    ag[mi][nj] = __builtin_amdgcn_mfma_f32_32x32x16_bf16(af[mi], bg[nj], ag[mi][nj], 0, 0, 0);
                    au[mi][nj] = __builtin_amdgcn_mfma_f32_32x32x16_bf16(af[mi], bu[nj], au[mi][nj], 0, 0, 0);
                }
        }
    }

#pragma unroll
    for (int mi = 0; mi < 2; ++mi)
#pragma unroll
        for (int nj = 0; nj < 2; ++nj) {
            int col = n0 + wn + nj * 32 + l32;
#pragma unroll
            for (int reg = 0; reg < 16; ++reg) {
                int row = m0 + wm + mi * 32 + (reg & 3) + 8 * (reg >> 2) + 4 * half;
                float g = ag[mi][nj][reg], u = au[mi][nj][reg];
                float s = g / (1.f + __expf(-g));
                H[(long long)row * ldh + col] = f2b(s * u);
            }
        }
}

// ---------- triangular P GEMM: P[b, i*256+m, j*256+n] = sum_f h_i[m,f] h_j[n,f], j<i ----------
// 1D grid of 960; decode keeps the 4 tiles of one pair on ONE XCD (lin%8 == pair%8)
// and consecutive same-i pairs on the same XCD (h_i stays L2-hot).
__global__ __launch_bounds__(256, 4)
void k_gemm_tri(const ushort_t* __restrict__ H, ushort_t* __restrict__ P,
                int K, int ldh, int ldp, long long sHb, long long sPb) {
    __shared__ __attribute__((aligned(16))) ushort_t sA[BM * BK];
    __shared__ __attribute__((aligned(16))) ushort_t sB[BN * BK];

    const int lin = blockIdx.x;
    const int g = lin >> 5, w = lin & 31;
    const int xk = w & 7, t = w >> 3;
    int pairIdx = g * 8 + xk;            // 0..239
    const int bb = pairIdx / 120;
    int p = pairIdx % 120;
    int i = 1, rem = p;
    while (rem >= i) { rem -= i; ++i; }
    const int j = rem;
    const int m0 = (t >> 1) * BM, n0 = (t & 1) * BN;

    const ushort_t* Ab = H + bb * sHb + (long long)(i * 256 + m0) * ldh;
    const ushort_t* Bb = H + bb * sHb + (long long)(j * 256 + n0) * ldh;

    const int tid = threadIdx.x;
    const int lane = tid & 63, l32 = lane & 31, half = lane >> 5;
    const int wave = tid >> 6;
    const int wm = (wave >> 1) * 64, wn = (wave & 1) * 64;

    f32x16 acc[2][2];
#pragma unroll
    for (int a = 0; a < 2; ++a)
#pragma unroll
        for (int c = 0; c < 2; ++c) acc[a][c] = (f32x16)(0.f);

    for (int k0 = 0; k0 < K; k0 += BK) {
        __syncthreads();
        stage_tile(Ab, ldh, k0, sA, tid);
        stage_tile(Bb, ldh, k0, sB, tid);
        __syncthreads();
#pragma unroll
        for (int ks = 0; ks < 4; ++ks) {
            bf16x8 af[2], bfr[2];
#pragma unroll
            for (int mi = 0; mi < 2; ++mi)
                af[mi] = ldfrag(sA, wm + mi * 32 + l32, ks * 2 + half);
#pragma unroll
            for (int nj = 0; nj < 2; ++nj)
                bfr[nj] = ldfrag(sB, wn + nj * 32 + l32, ks * 2 + half);
#pragma unroll
            for (int mi = 0; mi < 2; ++mi)
#pragma unroll
                for (int nj = 0; nj < 2; ++nj)
                    acc[mi][nj] = __builtin_amdgcn_mfma_f32_32x32x16_bf16(af[mi], bfr[nj], acc[mi][nj], 0, 0, 0);
        }
    }

    ushort_t* Pp = P + bb * sPb;
#pragma unroll
    for (int mi = 0; mi < 2; ++mi)
#pragma unroll
        for (int nj = 0; nj < 2; ++nj) {
            int col = j * 256 + n0 + wn + nj * 32 + l32;
#pragma unroll
            for (int reg = 0; reg < 16; ++reg) {
                int row = i * 256 + m0 + wm + mi * 32 + (reg & 3) + 8 * (reg >> 2) + 4 * half;
                Pp[(long long)row * ldp + col] = f2b(acc[mi][nj][reg]);
            }
        }
}

// ---------- fused output GEMM: out[b,i] = [h_i | P_i,0:i*C] @ [wdown | tpT]^T ----------
// K = 4096 + i*256; all operand lds are 4096. LR pre-folded into tpT. fp32 store.
__global__ __launch_bounds__(256, 4)
void k_gemm_out(const ushort_t* __restrict__ h, const ushort_t* __restrict__ wdown,
                const ushort_t* __restrict__ P, const ushort_t* __restrict__ tpT,
                float* __restrict__ out) {
    constexpr int T = 4096, D = 1024, F = 4096, C = 256, K1 = 4096;
    __shared__ __attribute__((aligned(16))) ushort_t sA[BM * BK];
    __shared__ __attribute__((aligned(16))) ushort_t sB[BN * BK];

    const int z = blockIdx.z, bb = z >> 4, ii = z & 15;
    const int K2 = ii * C;
    int m0, n0;
    tile_decode(m0, n0);

    const ushort_t* A1 = h + (long long)bb * T * F + (long long)(ii * C + m0) * F;
    const ushort_t* B1 = wdown + (long long)n0 * F;
    const ushort_t* A2 = P + (long long)bb * T * T + (long long)(ii * C + m0) * T;
    const ushort_t* B2 = tpT + (long long)bb * D * T + (long long)n0 * T;

    const int tid = threadIdx.x;
    const int lane = tid & 63, l32 = lane & 31, half = lane >> 5;
    const int wave = tid >> 6;
    const int wm = (wave >> 1) * 64, wn = (wave & 1) * 64;

    f32x16 acc[2][2];
#pragma unroll
    for (int i = 0; i < 2; ++i)
#pragma unroll
        for (int j = 0; j < 2; ++j) acc[i][j] = (f32x16)(0.f);

    const int K = K1 + K2;
    for (int k0 = 0; k0 < K; k0 += BK) {
        const ushort_t* As = (k0 < K1) ? A1 + k0 : A2 + (k0 - K1);
        const ushort_t* Bs = (k0 < K1) ? B1 + k0 : B2 + (k0 - K1);
        __syncthreads();
        stage_tile(As, 4096, 0, sA, tid);
        stage_tile(Bs, 4096, 0, sB, tid);
        __syncthreads();
#pragma unroll
        for (int ks = 0; ks < 4; ++ks) {
            bf16x8 af[2], bfr[2];
#pragma unroll
            for (int mi = 0; mi < 2; ++mi)
                af[mi] = ldfrag(sA, wm + mi * 32 + l32, ks * 2 + half);
#pragma unroll
            for (int nj = 0; nj < 2; ++nj)
                bfr[nj] = ldfrag(sB, wn + nj * 32 + l32, ks * 2 + half);
#pragma unroll
            for (int mi = 0; mi < 2; ++mi)
#pragma unroll
                for (int nj = 0; nj < 2; ++nj)
                    acc[mi][nj] = __builtin_amdgcn_mfma_f32_32x32x16_bf16(af[mi], bfr[nj], acc[mi][nj], 0, 0, 0);
        }
    }

    float* Op = out + (long long)bb * T * D + (long long)ii * C * D;
#pragma unroll
    for (int mi = 0; mi < 2; ++mi)
#pragma unroll
        for (int nj = 0; nj < 2; ++nj) {
            int col = n0 + wn + nj * 32 + l32;
#pragma unroll
            for (int reg = 0; reg < 16; ++reg) {
                int row = m0 + wm + mi * 32 + (reg & 3) + 8 * (reg >> 2) + 4 * half;
                Op[(long long)row * D + col] = acc[mi][nj][reg];
            }
        }
}

// ---------- launch ----------
extern "C" void kernel_launch(void* const* d_in, const int* in_sizes, int n_in,
                              void* d_out, int out_size, void* d_ws, size_t ws_size,
                              hipStream_t stream) {
    const float* x         = (const float*)d_in[0];
    const float* ttt_tgt   = (const float*)d_in[1];
    const float* w_gate_up = (const float*)d_in[2];
    const float* w_down    = (const float*)d_in[3];
    const float* ttt_proj  = (const float*)d_in[4];
    const float* conv_w    = (const float*)d_in[5];
    const float* conv_b    = (const float*)d_in[6];
    float* out = (float*)d_out;
    (void)in_sizes; (void)n_in; (void)out_size; (void)ws_size;

    constexpr int Bb = 2, T = 4096, D = 1024, F = 4096, C = 256;
    constexpr float LR = 0.01f;

    // workspace (154 MB):
    //   [0,64M): x_bf(16M) | wgu_bf(16M) | t_bf(16M) | scratch  -> later aliased by P (B,T,T) bf16
    //   [64M..): proj_bf 2M | wdown_bf 8M | tpT 16M | h 64M
    char* ws = (char*)d_ws;
    ushort_t* x_bf     = (ushort_t*)(ws);
    ushort_t* wgu_bf   = (ushort_t*)(ws + 16777216LL);
    ushort_t* t_bf     = (ushort_t*)(ws + 2 * 16777216LL);
    ushort_t* P        = (ushort_t*)(ws);
    ushort_t* proj_bf  = (ushort_t*)(ws + 67108864LL);
    ushort_t* wdown_bf = (ushort_t*)(ws + 67108864LL + 2097152LL);
    ushort_t* tpT      = (ushort_t*)(ws + 67108864LL + 2097152LL + 8388608LL);
    ushort_t* h        = (ushort_t*)(ws + 67108864LL + 2097152LL + 8388608LL + 16777216LL);

    // 1) fused prep: converts + causal conv  (21504 cvt blocks + 32768 conv blocks)
    k_prep<<<21504 + 32768, 256, 0, stream>>>(x, w_gate_up, ttt_proj, w_down,
                                              ttt_tgt, conv_w, conv_b,
                                              x_bf, wgu_bf, proj_bf, wdown_bf, t_bf);

    // 2) tpT[b] = LR * (proj @ t[b]^T) : M=D, N=T, K=D -> bf16 (B,D,T)
    k_gemm_nt<<<dim3(T / BN, D / BM, Bb), 256, 0, stream>>>(
        proj_bf, t_bf, tpT, D, D, D, T,
        0, (long long)T * D, (long long)D * T, LR);

    // 3) h = silu(x@Wg^T)*(x@Wu^T) : M=B*T, N=F, K=D
    k_gemm_silu<<<dim3(F / BN, (Bb * T) / BM, 1), 256, 0, stream>>>(
        x_bf, wgu_bf, wgu_bf + (long long)F * D, h, D, D, D, F);

    // 4) P lower chunk-blocks: P[b, i*C.., j*C..] = h_i h_j^T, j<i  (XCD-coherent 1D grid)
    k_gemm_tri<<<dim3(960, 1, 1), 256, 0, stream>>>(
        h, P, F, F, T, (long long)T * F, (long long)T * T);

    // 5) out[b,i] = [h_i | P] @ [wdown | LR*tpT]^T  (variable K = 4096 + i*256)
    k_gemm_out<<<dim3(D / BN, C / BM, Bb * 16), 256, 0, stream>>>(
        h, wdown_bf, P, tpT, out);
}